// Round 8
// baseline (95.770 us; speedup 1.0000x reference)
//
#include <hip/hip_runtime.h>

// MinibatchDiscrimination: B=512, IN=512, OUT=64, KD=8 (fp32 in/out)
// out[i, 0:512] = x[i, :]
// out[i, 512+o] = sum_j exp(-sum_k |M[i,o,k] - M[j,o,k]|),  M = x @ T
//
// R8: two kernels.
//  K1 gemm : grid 256 = (ib 8 x nb 32), 512 thr. Waves 0-3: MFMA 16x16x32
//            bf16 (A = x fp32 packed in-reg, B = T-slice LDS-transposed).
//            Waves 4-7: x -> out[:,0:512) copy + zero out[:,512:576)
//            (atomic targets). C -> LDS -> coalesced float4 Mt stores.
//  K2 pairs: grid 512 = (o, jc of 64 j) x 512 thr -> 2 blocks/CU, 4 waves/SIMD.
//            Wave w owns 8-j window; those 64 floats hoisted to REGISTERS once
//            (16 broadcast ds_read_b128) -> zero in-loop LDS traffic.
//            8 i/thread from coalesced global Mt. Cross-wave LDS reduction,
//            one atomicAdd per (i,o) per block.

#define B_    512
#define IN_   512
#define OUT_  64
#define KD_   8
#define ROW_  576
#define ROW4_ 144

typedef short short8 __attribute__((ext_vector_type(8)));
typedef float f32x4  __attribute__((ext_vector_type(4)));

__device__ __forceinline__ unsigned short f2bf(float f) {
    return (unsigned short)((__float_as_uint(f) + 0x8000u) >> 16);
}
__device__ __forceinline__ unsigned pack_bf2(float lo, float hi) {
    unsigned a = (__float_as_uint(lo) + 0x8000u) >> 16;
    unsigned b = (__float_as_uint(hi) + 0x8000u) & 0xFFFF0000u;
    return a | b;
}

// ---------------- K1: fused transpose + GEMM + out init ---------------------
__global__ __launch_bounds__(512)
void gemm_kernel(const float* __restrict__ x, const float* __restrict__ T,
                 float* __restrict__ Mt, float* __restrict__ out) {
    __shared__ unsigned short Tt[16][520];   // bf16 T-slice transposed
    __shared__ float Cs[64][17];             // C staging for coalesced Mt
    int t  = threadIdx.x;
    int bx = blockIdx.x;
    int nb = bx & 31, ib = bx >> 5;
    int n0 = nb * 16;

    {   // stage Tt[c][k] = bf16(T[k][n0+c]) with all 8 waves
        int c  = t & 15;
        int kb = t >> 4;                     // 0..31
        #pragma unroll
        for (int p = 0; p < 16; ++p) {
            int k = kb + p * 32;
            Tt[c][k] = f2bf(T[k * 512 + n0 + c]);
        }
    }
    __syncthreads();

    int lane = t & 63, w = t >> 6;
    int r = lane & 15, q = lane >> 4;

    if (w < 4) {
        int i0 = ib * 64 + w * 16;
        const float* pa = x + (i0 + r) * 512 + q * 8;
        f32x4 acc = {0.f, 0.f, 0.f, 0.f};
        #pragma unroll
        for (int kt = 0; kt < 16; ++kt) {
            float4 f0 = *(const float4*)(pa + kt * 32);
            float4 f1 = *(const float4*)(pa + kt * 32 + 4);
            union { unsigned u[4]; short8 v; } A;
            A.u[0] = pack_bf2(f0.x, f0.y);
            A.u[1] = pack_bf2(f0.z, f0.w);
            A.u[2] = pack_bf2(f1.x, f1.y);
            A.u[3] = pack_bf2(f1.z, f1.w);
            short8 Bv = *(const short8*)&Tt[r][q * 8 + kt * 32];
            acc = __builtin_amdgcn_mfma_f32_16x16x32_bf16(A.v, Bv, acc, 0, 0, 0);
        }
        #pragma unroll
        for (int rr = 0; rr < 4; ++rr)
            Cs[w * 16 + q * 4 + rr][r] = acc[rr];
    } else {
        // x -> out cols [0,512): 256 float4 per block
        int v  = bx * 256 + (t - 256);       // [0, 65536)
        int i  = v >> 7;
        int c4 = v & 127;
        ((float4*)out)[i * ROW4_ + c4] = ((const float4*)x)[v];
        // zero out cols [512,576): 32 float4 per block (atomic targets)
        if (t < 288) {
            int idx = bx * 32 + (t - 256);   // [0, 8192)
            int row = idx >> 4;
            int c4z = 128 + (idx & 15);
            ((float4*)out)[row * ROW4_ + c4z] = make_float4(0.f, 0.f, 0.f, 0.f);
        }
    }
    __syncthreads();

    // coalesced Mt write: block owns o = nb*2 + h, rows ib*64..+64
    if (t < 256) {
        int h   = t >> 7;
        int idx = t & 127;
        int ii  = idx >> 1;
        int kq  = (idx & 1) * 4;
        int o   = nb * 2 + h;
        float4 v;
        v.x = Cs[ii][h * 8 + kq + 0];
        v.y = Cs[ii][h * 8 + kq + 1];
        v.z = Cs[ii][h * 8 + kq + 2];
        v.w = Cs[ii][h * 8 + kq + 3];
        *(float4*)(Mt + o * (B_ * KD_) + (ib * 64 + ii) * KD_ + kq) = v;
    }
}

// ---------------- K2: all-pairs L1 + exp (register-hoisted j) ---------------
__global__ __launch_bounds__(512, 4)
void pairs_kernel(const float* __restrict__ Mt, float* __restrict__ out) {
    __shared__ float s[64][KD_];             // 2 KB: block's 64-j window
    __shared__ float s2[8][B_];              // 16 KB: per-wave partials
    int t  = threadIdx.x;
    int bx = blockIdx.x;
    int o  = bx >> 3;
    int jc = bx & 7;
    const float* base = Mt + o * (B_ * KD_);

    if (t < 128)
        ((float4*)s)[t] = ((const float4*)(base + jc * 64 * KD_))[t];
    __syncthreads();

    int lane = t & 63, w = t >> 6;

    // hoist this wave's 8-j window into registers (broadcast reads, once)
    float4 sj[16];
    #pragma unroll
    for (int jj = 0; jj < 8; ++jj) {
        sj[jj * 2 + 0] = *(const float4*)&s[w * 8 + jj][0];
        sj[jj * 2 + 1] = *(const float4*)&s[w * 8 + jj][4];
    }

    #pragma unroll
    for (int ii = 0; ii < 8; ++ii) {
        int i = lane + ii * 64;
        const float* p = base + i * KD_;
        float4 lo = *(const float4*)p;
        float4 hi = *(const float4*)(p + 4);
        float acc = 0.f;
        #pragma unroll
        for (int jj = 0; jj < 8; ++jj) {
            float4 a = sj[jj * 2 + 0];
            float4 b = sj[jj * 2 + 1];
            float d = fabsf(lo.x - a.x) + fabsf(lo.y - a.y)
                    + fabsf(lo.z - a.z) + fabsf(lo.w - a.w)
                    + fabsf(hi.x - b.x) + fabsf(hi.y - b.y)
                    + fabsf(hi.z - b.z) + fabsf(hi.w - b.w);
            acc += __expf(-d);
        }
        s2[w][i] = acc;
    }
    __syncthreads();

    // reduce 8 waves, one atomic per (i, o)
    float v = 0.f;
    #pragma unroll
    for (int ww = 0; ww < 8; ++ww) v += s2[ww][t];
    atomicAdd(&out[t * ROW_ + IN_ + o], v);
}

extern "C" void kernel_launch(void* const* d_in, const int* in_sizes, int n_in,
                              void* d_out, int out_size, void* d_ws, size_t ws_size,
                              hipStream_t stream) {
    const float* x = (const float*)d_in[0];   // [512, 512]
    const float* T = (const float*)d_in[1];   // [512, 64, 8]
    float* out = (float*)d_out;               // [512, 576]
    float* Mt  = (float*)d_ws;                // [64][512][8] fp32, 1 MB

    gemm_kernel<<<256, 512, 0, stream>>>(x, T, Mt, out);
    pairs_kernel<<<512, 512, 0, stream>>>(Mt, out);
}

// Round 9
// 73.149 us; speedup vs baseline: 1.3092x; 1.3092x over previous
//
#include <hip/hip_runtime.h>

// MinibatchDiscrimination: B=512, IN=512, OUT=64, KD=8 (fp32 in/out)
// out[i, 0:512] = x[i, :]
// out[i, 512+o] = sum_j exp(-sum_k |M[i,o,k] - M[j,o,k]|),  M = x @ T
//
// R9: two kernels, no atomics anywhere.
//  K1 gemm : 256 blocks x 256 thr (R4's best-measured shape). 4 waves:
//            all stage T-slice -> LDS bf16 transposed; MFMA 16x16x32
//            (A = x fp32 packed in-reg); C -> LDS -> coalesced float4 Mt.
//  K2 pairs: 512 blocks = (o, ic of 64 i) x 512 thr -> 2 blocks/CU,
//            4 waves/SIMD (2x R7's latency hiding). 1 i per lane; wave w
//            owns j-window [w*64,+64) -> wave-uniform LDS broadcast reads.
//            Cross-wave LDS reduce -> exclusive plain store.
//            x -> out copy folded in (hidden under compute).

#define B_    512
#define IN_   512
#define OUT_  64
#define KD_   8
#define ROW_  576
#define ROW4_ 144

typedef short short8 __attribute__((ext_vector_type(8)));
typedef float f32x4  __attribute__((ext_vector_type(4)));

__device__ __forceinline__ unsigned short f2bf(float f) {
    return (unsigned short)((__float_as_uint(f) + 0x8000u) >> 16);
}
__device__ __forceinline__ unsigned pack_bf2(float lo, float hi) {
    unsigned a = (__float_as_uint(lo) + 0x8000u) >> 16;
    unsigned b = (__float_as_uint(hi) + 0x8000u) & 0xFFFF0000u;
    return a | b;
}

// ---------------- K1: fused transpose + GEMM --------------------------------
__global__ __launch_bounds__(256)
void gemm_kernel(const float* __restrict__ x, const float* __restrict__ T,
                 float* __restrict__ Mt) {
    __shared__ unsigned short Tt[16][520];   // bf16 T-slice transposed
    __shared__ float Cs[64][17];             // C staging for coalesced Mt
    int t  = threadIdx.x;
    int bx = blockIdx.x;
    int nb = bx & 31, ib = bx >> 5;
    int n0 = nb * 16;

    {   // stage Tt[c][k] = bf16(T[k][n0+c])
        int c  = t & 15;
        int kb = t >> 4;                     // 0..15
        #pragma unroll
        for (int p = 0; p < 32; ++p) {
            int k = kb + p * 16;
            Tt[c][k] = f2bf(T[k * 512 + n0 + c]);
        }
    }
    __syncthreads();

    int lane = t & 63, w = t >> 6;
    int r = lane & 15, q = lane >> 4;

    {   // MFMA: wave w owns i-rows [ib*64 + w*16, +16)
        int i0 = ib * 64 + w * 16;
        const float* pa = x + (i0 + r) * 512 + q * 8;
        f32x4 acc = {0.f, 0.f, 0.f, 0.f};
        #pragma unroll
        for (int kt = 0; kt < 16; ++kt) {
            float4 f0 = *(const float4*)(pa + kt * 32);
            float4 f1 = *(const float4*)(pa + kt * 32 + 4);
            union { unsigned u[4]; short8 v; } A;
            A.u[0] = pack_bf2(f0.x, f0.y);
            A.u[1] = pack_bf2(f0.z, f0.w);
            A.u[2] = pack_bf2(f1.x, f1.y);
            A.u[3] = pack_bf2(f1.z, f1.w);
            short8 Bv = *(const short8*)&Tt[r][q * 8 + kt * 32];
            acc = __builtin_amdgcn_mfma_f32_16x16x32_bf16(A.v, Bv, acc, 0, 0, 0);
        }
        // C/D map: value rr of lane -> row q*4+rr, col r
        #pragma unroll
        for (int rr = 0; rr < 4; ++rr)
            Cs[w * 16 + q * 4 + rr][r] = acc[rr];
    }
    __syncthreads();

    // coalesced Mt write: block owns o = nb*2 + h, rows ib*64..+64
    {
        int h   = t >> 7;                    // 0..1
        int idx = t & 127;
        int ii  = idx >> 1;                  // 0..63
        int kq  = (idx & 1) * 4;             // 0 or 4
        int o   = nb * 2 + h;
        float4 v;
        v.x = Cs[ii][h * 8 + kq + 0];
        v.y = Cs[ii][h * 8 + kq + 1];
        v.z = Cs[ii][h * 8 + kq + 2];
        v.w = Cs[ii][h * 8 + kq + 3];
        *(float4*)(Mt + o * (B_ * KD_) + (ib * 64 + ii) * KD_ + kq) = v;
    }
}

// ---------------- K2: all-pairs L1 + exp + x-copy ---------------------------
__global__ __launch_bounds__(512)
void pairs_kernel(const float* __restrict__ Mt, const float* __restrict__ x,
                  float* __restrict__ out) {
    __shared__ float s[B_][KD_];             // 16 KB: full o-slice
    __shared__ float s2[8][64];              // 2 KB: per-wave partials
    int t  = threadIdx.x;
    int bx = blockIdx.x;
    int o  = bx >> 3;
    int ic = bx & 7;                         // i-range [ic*64, +64)
    const float* base = Mt + o * (B_ * KD_);

    ((float4*)s)[t]       = ((const float4*)base)[t];
    ((float4*)s)[t + 512] = ((const float4*)base)[t + 512];

    // side job: x -> out cols [0,512); 128 float4 per block (512*128 = 65536)
    if (t < 128) {
        int v  = bx * 128 + t;
        int i  = v >> 7;
        int c4 = v & 127;
        ((float4*)out)[i * ROW4_ + c4] = ((const float4*)x)[v];
    }
    __syncthreads();

    int lane = t & 63, w = t >> 6;
    int i = ic * 64 + lane;                  // this lane's single i
    float4 lo = *(const float4*)&s[i][0];
    float4 hi = *(const float4*)&s[i][4];

    float acc = 0.f;
    const float* sj = &s[w * 64][0];         // wave-uniform -> LDS broadcast
    #pragma unroll 4
    for (int jj = 0; jj < 64; ++jj) {
        float v0 = sj[0], v1 = sj[1], v2 = sj[2], v3 = sj[3];
        float v4 = sj[4], v5 = sj[5], v6 = sj[6], v7 = sj[7];
        sj += KD_;
        float d = fabsf(lo.x - v0) + fabsf(lo.y - v1)
                + fabsf(lo.z - v2) + fabsf(lo.w - v3)
                + fabsf(hi.x - v4) + fabsf(hi.y - v5)
                + fabsf(hi.z - v6) + fabsf(hi.w - v7);
        acc += __expf(-d);
    }
    s2[w][lane] = acc;
    __syncthreads();

    // exclusive final store: this block owns (o, i) for i in [ic*64, +64)
    if (t < 64) {
        float v = 0.f;
        #pragma unroll
        for (int ww = 0; ww < 8; ++ww) v += s2[ww][t];
        out[(ic * 64 + t) * ROW_ + IN_ + o] = v;
    }
}

extern "C" void kernel_launch(void* const* d_in, const int* in_sizes, int n_in,
                              void* d_out, int out_size, void* d_ws, size_t ws_size,
                              hipStream_t stream) {
    const float* x = (const float*)d_in[0];   // [512, 512]
    const float* T = (const float*)d_in[1];   // [512, 64, 8]
    float* out = (float*)d_out;               // [512, 576]
    float* Mt  = (float*)d_ws;                // [64][512][8] fp32, 1 MB

    gemm_kernel<<<256, 256, 0, stream>>>(x, T, Mt);
    pairs_kernel<<<512, 512, 0, stream>>>(Mt, x, out);
}